// Round 9
// baseline (245.837 us; speedup 1.0000x reference)
//
#include <hip/hip_runtime.h>

// Problem constants (from reference): N=512, OBS=32, H=128, M=128, L=3
#define NA 512
#define NOBS 32
#define NH 128

typedef const float* fp32p;
typedef __attribute__((ext_vector_type(8))) short bf16x8;
typedef __attribute__((ext_vector_type(4))) float f32x4;
typedef __attribute__((ext_vector_type(16))) float f32x16;

// packed 2xf32 -> 2xbf16 (RNE) in one instruction (gfx950); lo -> bits[15:0]
__device__ __forceinline__ unsigned cvt_pk_bf16(float lo, float hi) {
    unsigned r;
    asm("v_cvt_pk_bf16_f32 %0, %1, %2" : "=v"(r) : "v"(lo), "v"(hi));
    return r;
}

__device__ __forceinline__ bf16x8 wfrag_f4(const float* p) {  // 16B-aligned
    float4 u = *(const float4*)p;
    float4 v = *(const float4*)(p + 4);
    union { unsigned w[4]; bf16x8 f; } r;
    r.w[0] = cvt_pk_bf16(u.x, u.y);
    r.w[1] = cvt_pk_bf16(u.z, u.w);
    r.w[2] = cvt_pk_bf16(v.x, v.y);
    r.w[3] = cvt_pk_bf16(v.z, v.w);
    return r.f;
}

// LDS row stride (shorts). Multiple of 8 (16B alignment for ds_read_b128 --
// R7 lesson) and 136 keeps b128 reads at the 8-access/bank BW floor.
// R8 lesson: SQ_LDS_BANK_CONFLICT ~4.3M is the b128 read-floor signature
// (identical across store rewrites), NOT a fixable conflict stream.
#define HSTR 136

// ----------------------------------------- fused encoder + layer-0 ab ------
// grid 512 x 512 (proven): GEMV phases, 4 lanes per output row.
__global__ __launch_bounds__(512) void enc_ab_kernel(
    fp32p obs, fp32p eW1, fp32p eb1, fp32p eW2, fp32p eb2, fp32p eW3, fp32p eb3,
    fp32p mW1, float* __restrict__ z, float* __restrict__ A, float* __restrict__ B) {
    const int i = blockIdx.x;
    const int t = threadIdx.x;
    const int nn = t >> 2;   // output row 0..127
    const int ks = t & 3;    // k-segment

    __shared__ float xs0[NOBS];
    __shared__ float part[4 * NH];
    __shared__ float part2[4 * NH];
    __shared__ float hx[NH], hy[NH], zz[NH];

    if (t < NOBS) xs0[t] = obs[(size_t)i * NOBS + t];
    __syncthreads();
    // L1: K=32 (8 k per lane)
    {
        const float* wr = eW1 + (size_t)nn * NOBS + ks * 8;
        const float4 w0 = *(const float4*)wr;
        const float4 w1 = *(const float4*)(wr + 4);
        const float4 x0 = *(const float4*)&xs0[ks * 8];
        const float4 x1 = *(const float4*)&xs0[ks * 8 + 4];
        part[ks * NH + nn] = w0.x * x0.x + w0.y * x0.y + w0.z * x0.z + w0.w * x0.w +
                             w1.x * x1.x + w1.y * x1.y + w1.z * x1.z + w1.w * x1.w;
    }
    __syncthreads();
    if (t < NH)
        hx[t] = fmaxf(eb1[t] + part[t] + part[NH + t] + part[2 * NH + t] + part[3 * NH + t], 0.f);
    __syncthreads();
    // L2: K=128
    {
        const float* wr = eW2 + (size_t)nn * NH + ks * 4;
        float p = 0.f;
        #pragma unroll
        for (int it = 0; it < 8; ++it) {
            const float4 wv = *(const float4*)(wr + it * 16);
            const float4 xv = *(const float4*)&hx[it * 16 + ks * 4];
            p += wv.x * xv.x + wv.y * xv.y + wv.z * xv.z + wv.w * xv.w;
        }
        part[ks * NH + nn] = p;
    }
    __syncthreads();
    if (t < NH)
        hy[t] = fmaxf(eb2[t] + part[t] + part[NH + t] + part[2 * NH + t] + part[3 * NH + t], 0.f);
    __syncthreads();
    // L3: K=128, no relu -> z
    {
        const float* wr = eW3 + (size_t)nn * NH + ks * 4;
        float p = 0.f;
        #pragma unroll
        for (int it = 0; it < 8; ++it) {
            const float4 wv = *(const float4*)(wr + it * 16);
            const float4 xv = *(const float4*)&hy[it * 16 + ks * 4];
            p += wv.x * xv.x + wv.y * xv.y + wv.z * xv.z + wv.w * xv.w;
        }
        part[ks * NH + nn] = p;
    }
    __syncthreads();
    if (t < NH) {
        const float v = eb3[t] + part[t] + part[NH + t] + part[2 * NH + t] + part[3 * NH + t];
        z[(size_t)i * NH + t] = v;
        zz[t] = v;
    }
    __syncthreads();
    // ab layer 0 (K=128, row stride 257 -> dword loads)
    {
        const float* pr = mW1 + (size_t)nn * 257;
        float pa = 0.f, pb = 0.f;
        #pragma unroll
        for (int it = 0; it < 8; ++it) {
            #pragma unroll
            for (int j = 0; j < 4; ++j) {
                const int k = it * 16 + ks * 4 + j;
                const float x = zz[k];
                pa += x * pr[k];
                pb += x * pr[NH + k];
            }
        }
        part[ks * NH + nn] = pa;
        part2[ks * NH + nn] = pb;
    }
    __syncthreads();
    if (t < NH) {
        A[(size_t)i * NH + t] = part[t] + part[NH + t] + part[2 * NH + t] + part[3 * NH + t];
        B[(size_t)i * NH + t] = part2[t] + part2[NH + t] + part2[2 * NH + t] + part2[3 * NH + t];
    }
}

// -------------------------------------- fused message + update + next-ab ----
// R9 = R6/R8 loop skeleton (pipelined BUILD||GEMM2, HSTR=136) with the GEMM
// cores moved to mfma_f32_32x32x16_bf16: 32 FLOP per A-frag byte (2x the
// 16x16x32 rate) -> LDS read instrs AND MFMA issue count halve at equal
// FLOPs. Wave map: 8 waves = 2 row-groups (rg2) x 4 col-tiles (ntile); each
// wave does 2 j-tiles of 32 rows sequentially (TLP 4 waves/SIMD + BUILD
// overlap cover the 8-deep K chains). C/D layout (HW-verified): col=lane&31,
// row=(reg&3)+8*(reg>>2)+4*(lane>>5). h2 b16 store epilogue is naturally
// conflict-free at HSTR=136 (2 lanes/bank, same-dword halfword pairs).
// launch_bounds(512,2) = empirical 128-VGPR cap (R1/R2 calibration).
__global__ __launch_bounds__(512, 2) void msg_upd_kernel(
    const float* __restrict__ A, const float* __restrict__ B,
    fp32p pos, const float* __restrict__ zin,
    fp32p W1l, fp32p b1, fp32p W2, fp32p b2, fp32p W3, fp32p b3,
    fp32p uW1, fp32p ub1, fp32p uW2, fp32p ub2, fp32p uW3, fp32p ub3,
    fp32p msgW1n, int do_ab,
    float* __restrict__ zout, float* __restrict__ An, float* __restrict__ Bn) {
    const int i = blockIdx.x;
    const int t = threadIdx.x;
    const int lane = t & 63;
    const int w = t >> 6;
    const int l31 = lane & 31;
    const int hi = lane >> 5;
    const int hi8 = hi * 8;
    const int ntile = w & 3;           // col-tile 0..3 (32 cols)
    const int rg2 = w >> 2;            // row-group 0..1 (64 rows = 2 j-tiles)
    const int ncol32 = ntile * 32 + l31;

    __shared__ short h1s[128 * HSTR];  // 34816 B
    __shared__ short h2s[128 * HSTR];  // 34816 B
    __shared__ float distrow[NA];
    __shared__ float amrow[NH];        // A_i + b1 folded
    __shared__ float wdsr[NH];
    __shared__ float xs2[2 * NH];      // [z_i | msum_i]
    __shared__ float part[4 * NH];
    __shared__ float part2[4 * NH];
    __shared__ float hx[NH], hy[NH], hz[NH];

    if (t < NH) {
        amrow[t] = A[i * NH + t] + b1[t];
        wdsr[t]  = W1l[t * 257 + 256];
        xs2[t] = zin[(size_t)i * NH + t];
    }
    {
        const float2 pi = *(const float2*)&pos[2 * i];
        const float2 pj = *(const float2*)&pos[2 * t];
        const float dx = pi.x - pj.x, dy = pi.y - pj.y;
        const float s = dx * dx + dy * dy;
        distrow[t] = (t == i) ? 0.0f : sqrtf(s);
    }

    // register-resident weight fragments for 32x32x16 (B-operand):
    // lane: col = l31 (row ncol32 of W2/W3), k = kb*16 + hi*8 + e
    bf16x8 w2g[8], w3g[8];
    {
        const float* w2r = W2 + (size_t)ncol32 * NH + hi8;
        const float* w3r = W3 + (size_t)ncol32 * NH + hi8;
        #pragma unroll
        for (int kb = 0; kb < 8; ++kb) {
            w2g[kb] = wfrag_f4(w2r + kb * 16);
            w3g[kb] = wfrag_f4(w3r + kb * 16);
        }
    }
    const float b2n32 = b2[ncol32];

    const int m2 = lane * 2;
    float psum = 0.0f;

    __syncthreads();   // amrow/wdsr/distrow ready
    const float am0 = amrow[m2], am1 = amrow[m2 + 1];
    const float wd0 = wdsr[m2],  wd1 = wdsr[m2 + 1];

#define BUILD(c4_) do {                                                      \
        const int j0_ = (c4_) * 128;                                         \
        _Pragma("unroll")                                                    \
        for (int rr = 0; rr < 16; ++rr) {                                    \
            const int row_ = rr * 8 + w;                                     \
            const int jg_ = j0_ + row_;                                      \
            const float2 bv_ = *(const float2*)&B[(size_t)jg_ * NH + m2];    \
            const float d_ = distrow[jg_];                                   \
            const float v0_ = fmaxf(fmaf(d_, wd0, am0 + bv_.x), 0.0f);       \
            const float v1_ = fmaxf(fmaf(d_, wd1, am1 + bv_.y), 0.0f);       \
            *(unsigned*)&h1s[row_ * HSTR + m2] = cvt_pk_bf16(v0_, v1_);      \
        }                                                                    \
    } while (0)

#define ZERO16 {0.f,0.f,0.f,0.f,0.f,0.f,0.f,0.f,0.f,0.f,0.f,0.f,0.f,0.f,0.f,0.f}

#define GEMM1() do {                                                         \
        _Pragma("unroll")                                                    \
        for (int jt2 = 0; jt2 < 2; ++jt2) {                                  \
            const int jr0 = (rg2 * 2 + jt2) * 32;                            \
            f32x16 acc = ZERO16;                                             \
            const short* ar = &h1s[(jr0 + l31) * HSTR + hi8];                \
            _Pragma("unroll")                                                \
            for (int kb = 0; kb < 8; ++kb) {                                 \
                bf16x8 a = *(const bf16x8*)(ar + kb * 16);                   \
                acc = __builtin_amdgcn_mfma_f32_32x32x16_bf16(a, w2g[kb], acc, 0, 0, 0); \
            }                                                                \
            _Pragma("unroll")                                                \
            for (int rg_ = 0; rg_ < 16; ++rg_) {                             \
                const int rowl = (rg_ & 3) + 8 * (rg_ >> 2) + 4 * hi;        \
                const float v = fmaxf(acc[rg_] + b2n32, 0.f);                \
                h2s[(jr0 + rowl) * HSTR + ncol32] = (short)cvt_pk_bf16(v, v);\
            }                                                                \
        }                                                                    \
    } while (0)

#define GEMM2(c4_) do {                                                      \
        const int j0_ = (c4_) * 128;                                         \
        _Pragma("unroll")                                                    \
        for (int jt2 = 0; jt2 < 2; ++jt2) {                                  \
            const int jr0 = (rg2 * 2 + jt2) * 32;                            \
            f32x16 acc = ZERO16;                                             \
            const short* ar = &h2s[(jr0 + l31) * HSTR + hi8];                \
            _Pragma("unroll")                                                \
            for (int kb = 0; kb < 8; ++kb) {                                 \
                bf16x8 a = *(const bf16x8*)(ar + kb * 16);                   \
                acc = __builtin_amdgcn_mfma_f32_32x32x16_bf16(a, w3g[kb], acc, 0, 0, 0); \
            }                                                                \
            _Pragma("unroll")                                                \
            for (int rg_ = 0; rg_ < 16; ++rg_) {                             \
                const int jg_ = j0_ + jr0 + (rg_ & 3) + 8 * (rg_ >> 2) + 4 * hi; \
                if (jg_ != i) psum += acc[rg_];                              \
            }                                                                \
        }                                                                    \
    } while (0)

    // pipelined: BUILD(c4+1) overlaps GEMM2(c4); h1s/h2s ping-pong by phase
    BUILD(0);
    __syncthreads();       // h1s(0) ready
    GEMM1();               // h1s(0) -> h2s(0)
    for (int c4 = 0; c4 < 4; ++c4) {
        __syncthreads();   // h2s(c4) ready; h1s free (GEMM1 done)
        if (c4 < 3) {
            BUILD(c4 + 1); // -> h1s (overlaps GEMM2's MFMAs)
            GEMM2(c4);     // h2s -> psum
            __syncthreads();  // h1s(c4+1) ready; h2s fully consumed
            GEMM1();       // h1s(c4+1) -> h2s(c4+1)
        } else {
            GEMM2(c4);
        }
    }
#undef BUILD
#undef GEMM1
#undef GEMM2
#undef ZERO16

    // ---- msum: combine hi-halves (rows), cross-wave pair via part2 ----
    psum += __shfl_xor(psum, 32, 64);
    if (lane < 32) part2[rg2 * 128 + ncol32] = psum;
    __syncthreads();
    if (t < NH) xs2[NH + t] = part2[t] + part2[128 + t] + 511.0f * b3[t];
    __syncthreads();

    // ---- tail: update MLP (fp32 GEMV, 4 lanes per output row) ----
    const int nn = t >> 2;   // output row 0..127
    const int ks = t & 3;    // k-segment
    // L1: K=256
    {
        const float* wr = uW1 + (size_t)nn * 256 + ks * 4;
        float p = 0.f;
        #pragma unroll
        for (int it = 0; it < 16; ++it) {
            const float4 wv = *(const float4*)(wr + it * 16);
            const float4 xv = *(const float4*)&xs2[it * 16 + ks * 4];
            p += wv.x * xv.x + wv.y * xv.y + wv.z * xv.z + wv.w * xv.w;
        }
        part[ks * NH + nn] = p;
    }
    __syncthreads();
    if (t < NH)
        hx[t] = fmaxf(ub1[t] + part[t] + part[NH + t] + part[2 * NH + t] + part[3 * NH + t], 0.f);
    __syncthreads();
    // L2: K=128
    {
        const float* wr = uW2 + (size_t)nn * NH + ks * 4;
        float p = 0.f;
        #pragma unroll
        for (int it = 0; it < 8; ++it) {
            const float4 wv = *(const float4*)(wr + it * 16);
            const float4 xv = *(const float4*)&hx[it * 16 + ks * 4];
            p += wv.x * xv.x + wv.y * xv.y + wv.z * xv.z + wv.w * xv.w;
        }
        part[ks * NH + nn] = p;
    }
    __syncthreads();
    if (t < NH)
        hy[t] = fmaxf(ub2[t] + part[t] + part[NH + t] + part[2 * NH + t] + part[3 * NH + t], 0.f);
    __syncthreads();
    // L3: K=128, no relu -> zout + hz
    {
        const float* wr = uW3 + (size_t)nn * NH + ks * 4;
        float p = 0.f;
        #pragma unroll
        for (int it = 0; it < 8; ++it) {
            const float4 wv = *(const float4*)(wr + it * 16);
            const float4 xv = *(const float4*)&hy[it * 16 + ks * 4];
            p += wv.x * xv.x + wv.y * xv.y + wv.z * xv.z + wv.w * xv.w;
        }
        part[ks * NH + nn] = p;
    }
    __syncthreads();
    if (t < NH) {
        const float v = ub3[t] + part[t] + part[NH + t] + part[2 * NH + t] + part[3 * NH + t];
        zout[(size_t)i * NH + t] = v;
        hz[t] = v;
    }
    if (!do_ab) return;
    __syncthreads();
    // ab: A = z@Wi^T, B = z@Wj^T (K=128, row stride 257 -> dword loads)
    {
        const float* pr = msgW1n + (size_t)nn * 257;
        float pa = 0.f, pb = 0.f;
        #pragma unroll
        for (int it = 0; it < 8; ++it) {
            #pragma unroll
            for (int j = 0; j < 4; ++j) {
                const int k = it * 16 + ks * 4 + j;
                const float x = hz[k];
                pa += x * pr[k];
                pb += x * pr[NH + k];
            }
        }
        part[ks * NH + nn] = pa;
        part2[ks * NH + nn] = pb;
    }
    __syncthreads();
    if (t < NH) {
        An[(size_t)i * NH + t] = part[t] + part[NH + t] + part[2 * NH + t] + part[3 * NH + t];
        Bn[(size_t)i * NH + t] = part2[t] + part2[NH + t] + part2[2 * NH + t] + part2[3 * NH + t];
    }
}

// ---------------------------------------------------------------- host ------
extern "C" void kernel_launch(void* const* d_in, const int* in_sizes, int n_in,
                              void* d_out, int out_size, void* d_ws, size_t ws_size,
                              hipStream_t stream) {
    fp32p obs   = (fp32p)d_in[0];
    fp32p pos   = (fp32p)d_in[1];
    fp32p encW1 = (fp32p)d_in[2];  fp32p encb1 = (fp32p)d_in[3];
    fp32p encW2 = (fp32p)d_in[4];  fp32p encb2 = (fp32p)d_in[5];
    fp32p encW3 = (fp32p)d_in[6];  fp32p encb3 = (fp32p)d_in[7];
    fp32p msgW1 = (fp32p)d_in[8];  fp32p msgb1 = (fp32p)d_in[9];
    fp32p msgW2 = (fp32p)d_in[10]; fp32p msgb2 = (fp32p)d_in[11];
    fp32p msgW3 = (fp32p)d_in[12]; fp32p msgb3 = (fp32p)d_in[13];
    fp32p updW1 = (fp32p)d_in[14]; fp32p updb1 = (fp32p)d_in[15];
    fp32p updW2 = (fp32p)d_in[16]; fp32p updb2 = (fp32p)d_in[17];
    fp32p updW3 = (fp32p)d_in[18]; fp32p updb3 = (fp32p)d_in[19];

    // workspace (fp32): zA | zB | A0 | B0 | A1 | B1  (1.5 MB)
    float* ws = (float*)d_ws;
    float* zA = ws;
    float* zB = zA + NA * NH;
    float* A0 = zB + NA * NH;
    float* B0 = A0 + NA * NH;
    float* A1 = B0 + NA * NH;
    float* B1 = A1 + NA * NH;

    enc_ab_kernel<<<NA, 512, 0, stream>>>(obs, encW1, encb1, encW2, encb2,
                                          encW3, encb3, msgW1, zA, A0, B0);

    float* zin = zA;  float* zout = zB;
    float* Ac = A0;   float* Bc = B0;
    float* An = A1;   float* Bn = B1;
    for (int l = 0; l < 3; ++l) {
        const int do_ab = (l < 2);
        float* dst = (l == 2) ? (float*)d_out : zout;
        msg_upd_kernel<<<NA, 512, 0, stream>>>(Ac, Bc, pos, zin,
            msgW1 + (size_t)l * 128 * 257, msgb1 + l * 128,
            msgW2 + (size_t)l * 128 * 128, msgb2 + l * 128,
            msgW3 + (size_t)l * 128 * 128, msgb3 + l * 128,
            updW1 + (size_t)l * 256 * 128, updb1 + l * 128,
            updW2 + (size_t)l * 128 * 128, updb2 + l * 128,
            updW3 + (size_t)l * 128 * 128, updb3 + l * 128,
            msgW1 + (size_t)(l + 1 < 3 ? l + 1 : 0) * 128 * 257, do_ab,
            dst, An, Bn);
        float* tmp;
        tmp = zin; zin = zout; zout = tmp;
        tmp = Ac; Ac = An; An = tmp;
        tmp = Bc; Bc = Bn; Bn = tmp;
    }
}

// Round 10
// 207.762 us; speedup vs baseline: 1.1833x; 1.1833x over previous
//
#include <hip/hip_runtime.h>

// Problem constants (from reference): N=512, OBS=32, H=128, M=128, L=3
#define NA 512
#define NOBS 32
#define NH 128

typedef const float* fp32p;
typedef __attribute__((ext_vector_type(8))) short bf16x8;
typedef __attribute__((ext_vector_type(4))) float f32x4;

// packed 2xf32 -> 2xbf16 (RNE) in one instruction (gfx950); lo -> bits[15:0]
__device__ __forceinline__ unsigned cvt_pk_bf16(float lo, float hi) {
    unsigned r;
    asm("v_cvt_pk_bf16_f32 %0, %1, %2" : "=v"(r) : "v"(lo), "v"(hi));
    return r;
}

__device__ __forceinline__ bf16x8 wfrag_f4(const float* p) {  // 16B-aligned
    float4 u = *(const float4*)p;
    float4 v = *(const float4*)(p + 4);
    union { unsigned w[4]; bf16x8 f; } r;
    r.w[0] = cvt_pk_bf16(u.x, u.y);
    r.w[1] = cvt_pk_bf16(u.z, u.w);
    r.w[2] = cvt_pk_bf16(v.x, v.y);
    r.w[3] = cvt_pk_bf16(v.z, v.w);
    return r.f;
}

__device__ __forceinline__ bf16x8 wfrag_s(const float* p) {   // unaligned-safe
    union { unsigned w[4]; bf16x8 f; } r;
    r.w[0] = cvt_pk_bf16(p[0], p[1]);
    r.w[1] = cvt_pk_bf16(p[2], p[3]);
    r.w[2] = cvt_pk_bf16(p[4], p[5]);
    r.w[3] = cvt_pk_bf16(p[6], p[7]);
    return r.f;
}

// LDS row stride (shorts). Multiple of 8 (16B alignment for ds_read_b128 --
// R7 lesson) and 136 keeps b128 reads at the 8-access/bank BW floor.
// R8/R9 lesson: SQ_LDS_BANK_CONFLICT ~4.3M is the b128 read-floor signature,
// not a fixable conflict stream; 16x16x32 with 8 independent chains beats
// 32x32x16 (R9: same MFMA busy-time, worse epilogue + AGPR traffic).
#define HSTR 136

// ----------------------------------------- fused encoder + layer-0 ab ------
// R10: MFMA tile rewrite. 16 agents per block (grid 32), 8 waves x 16-col
// tiles, proven msg fragment layout (A: lane(q,c)->[m=c][k=q8+e]; D:
// [m=q*4+r][n=ncol]). L1 = one K=32 MFMA; L2/L3 = 4 MFMAs; ab = 8 MFMAs
// (Wi & Wj, scalar-loaded frags for the 257-stride rows). Replaces the
// 9-barrier-phase fp32 GEMV structure (one agent/block, 64 scalar loads in
// the ab phase) with ~6 barriers and 17 MFMAs/wave.
__global__ __launch_bounds__(512) void enc_ab_kernel(
    fp32p obs, fp32p eW1, fp32p eb1, fp32p eW2, fp32p eb2, fp32p eW3, fp32p eb3,
    fp32p mW1, float* __restrict__ z, float* __restrict__ A, float* __restrict__ B) {
    const int i0 = blockIdx.x * 16;
    const int t = threadIdx.x;
    const int lane = t & 63;
    const int w = t >> 6;
    const int q = lane >> 4;
    const int c = lane & 15;
    const int q8 = q * 8;
    const int ncol = w * 16 + c;

    __shared__ short ha[16 * HSTR];   // layer activations bf16 (ping)
    __shared__ short hb[16 * HSTR];   // (pong)

    // ---- L1: h1 = relu(obs @ eW1^T + eb1), one 16x16x32 MFMA ----
    {
        const bf16x8 af = wfrag_f4(obs + (size_t)(i0 + c) * NOBS + q8);
        const bf16x8 bf = wfrag_f4(eW1 + (size_t)ncol * NOBS + q8);
        f32x4 acc = {0.f, 0.f, 0.f, 0.f};
        acc = __builtin_amdgcn_mfma_f32_16x16x32_bf16(af, bf, acc, 0, 0, 0);
        const float bn = eb1[ncol];
        #pragma unroll
        for (int r = 0; r < 4; ++r) {
            const float v = fmaxf(acc[r] + bn, 0.f);
            ha[(q * 4 + r) * HSTR + ncol] = (short)cvt_pk_bf16(v, v);
        }
    }
    __syncthreads();
    // ---- L2: h2 = relu(h1 @ eW2^T + eb2) ----
    {
        f32x4 acc = {0.f, 0.f, 0.f, 0.f};
        const short* ar = &ha[c * HSTR + q8];
        #pragma unroll
        for (int kb = 0; kb < 4; ++kb) {
            const bf16x8 a = *(const bf16x8*)(ar + kb * 32);
            const bf16x8 b = wfrag_f4(eW2 + (size_t)ncol * NH + kb * 32 + q8);
            acc = __builtin_amdgcn_mfma_f32_16x16x32_bf16(a, b, acc, 0, 0, 0);
        }
        const float bn = eb2[ncol];
        #pragma unroll
        for (int r = 0; r < 4; ++r) {
            const float v = fmaxf(acc[r] + bn, 0.f);
            hb[(q * 4 + r) * HSTR + ncol] = (short)cvt_pk_bf16(v, v);
        }
    }
    __syncthreads();
    // ---- L3: z = h2 @ eW3^T + eb3 (fp32 out + bf16 LDS for ab) ----
    {
        f32x4 acc = {0.f, 0.f, 0.f, 0.f};
        const short* ar = &hb[c * HSTR + q8];
        #pragma unroll
        for (int kb = 0; kb < 4; ++kb) {
            const bf16x8 a = *(const bf16x8*)(ar + kb * 32);
            const bf16x8 b = wfrag_f4(eW3 + (size_t)ncol * NH + kb * 32 + q8);
            acc = __builtin_amdgcn_mfma_f32_16x16x32_bf16(a, b, acc, 0, 0, 0);
        }
        const float bn = eb3[ncol];
        #pragma unroll
        for (int r = 0; r < 4; ++r) {
            const float v = acc[r] + bn;
            z[(size_t)(i0 + q * 4 + r) * NH + ncol] = v;
            ha[(q * 4 + r) * HSTR + ncol] = (short)cvt_pk_bf16(v, v);
        }
    }
    __syncthreads();
    // ---- ab layer 0: A = z@Wi^T, B = z@Wj^T (mW1 rows stride 257) ----
    {
        f32x4 aa = {0.f, 0.f, 0.f, 0.f};
        f32x4 ab = {0.f, 0.f, 0.f, 0.f};
        const short* ar = &ha[c * HSTR + q8];
        const float* wrow = mW1 + (size_t)ncol * 257;
        #pragma unroll
        for (int kb = 0; kb < 4; ++kb) {
            const bf16x8 a = *(const bf16x8*)(ar + kb * 32);
            const bf16x8 bi = wfrag_s(wrow + kb * 32 + q8);
            const bf16x8 bj = wfrag_s(wrow + 128 + kb * 32 + q8);
            aa = __builtin_amdgcn_mfma_f32_16x16x32_bf16(a, bi, aa, 0, 0, 0);
            ab = __builtin_amdgcn_mfma_f32_16x16x32_bf16(a, bj, ab, 0, 0, 0);
        }
        #pragma unroll
        for (int r = 0; r < 4; ++r) {
            A[(size_t)(i0 + q * 4 + r) * NH + ncol] = aa[r];
            B[(size_t)(i0 + q * 4 + r) * NH + ncol] = ab[r];
        }
    }
}

// -------------------------------------- fused message + update + next-ab ----
// R8 EXACT (proven 43.0us): pipelined BUILD||GEMM2, HSTR=136, 16x16x32 MFMA,
// lane-pair-transpose h2 store epilogue (2 dword stores/jt, 2 lanes/bank).
__global__ __launch_bounds__(512) void msg_upd_kernel(
    const float* __restrict__ A, const float* __restrict__ B,
    fp32p pos, const float* __restrict__ zin,
    fp32p W1l, fp32p b1, fp32p W2, fp32p b2, fp32p W3, fp32p b3,
    fp32p uW1, fp32p ub1, fp32p uW2, fp32p ub2, fp32p uW3, fp32p ub3,
    fp32p msgW1n, int do_ab,
    float* __restrict__ zout, float* __restrict__ An, float* __restrict__ Bn) {
    const int i = blockIdx.x;
    const int t = threadIdx.x;
    const int lane = t & 63;
    const int w = t >> 6;
    const int q = lane >> 4;
    const int c = lane & 15;
    const int ncol = w * 16 + c;

    __shared__ short h1s[128 * HSTR];  // 34816 B
    __shared__ short h2s[128 * HSTR];  // 34816 B
    __shared__ float distrow[NA];
    __shared__ float amrow[NH];        // A_i + b1 folded
    __shared__ float wdsr[NH];
    __shared__ float xs2[2 * NH];      // [z_i | msum_i]
    __shared__ float part[4 * NH];
    __shared__ float part2[4 * NH];
    __shared__ float hx[NH], hy[NH], hz[NH];

    if (t < NH) {
        amrow[t] = A[i * NH + t] + b1[t];
        wdsr[t]  = W1l[t * 257 + 256];
        xs2[t] = zin[(size_t)i * NH + t];
    }
    {
        const float2 pi = *(const float2*)&pos[2 * i];
        const float2 pj = *(const float2*)&pos[2 * t];
        const float dx = pi.x - pj.x, dy = pi.y - pj.y;
        const float s = dx * dx + dy * dy;
        distrow[t] = (t == i) ? 0.0f : sqrtf(s);
    }

    // register-resident weight fragments (one 16-col n-tile per wave)
    bf16x8 w2f[4], w3f[4];
    {
        const float* w2r = W2 + (size_t)ncol * NH + q * 8;
        const float* w3r = W3 + (size_t)ncol * NH + q * 8;
        #pragma unroll
        for (int kb = 0; kb < 4; ++kb) {
            w2f[kb] = wfrag_f4(w2r + kb * 32);
            w3f[kb] = wfrag_f4(w3r + kb * 32);
        }
    }
    const float b2n = b2[ncol];

    const int m2 = lane * 2;
    float psum = 0.0f;

    __syncthreads();   // amrow/wdsr/distrow ready
    const float am0 = amrow[m2], am1 = amrow[m2 + 1];
    const float wd0 = wdsr[m2],  wd1 = wdsr[m2 + 1];

#define BUILD(c4_) do {                                                      \
        const int j0_ = (c4_) * 128;                                         \
        _Pragma("unroll")                                                    \
        for (int rr = 0; rr < 16; ++rr) {                                    \
            const int row_ = rr * 8 + w;                                     \
            const int jg_ = j0_ + row_;                                      \
            const float2 bv_ = *(const float2*)&B[(size_t)jg_ * NH + m2];    \
            const float d_ = distrow[jg_];                                   \
            const float v0_ = fmaxf(fmaf(d_, wd0, am0 + bv_.x), 0.0f);       \
            const float v1_ = fmaxf(fmaf(d_, wd1, am1 + bv_.y), 0.0f);       \
            *(unsigned*)&h1s[row_ * HSTR + m2] = cvt_pk_bf16(v0_, v1_);      \
        }                                                                    \
    } while (0)

#define GEMM1() do {                                                         \
        _Pragma("unroll")                                                    \
        for (int jt = 0; jt < 8; ++jt) {                                     \
            f32x4 acc = {0.f, 0.f, 0.f, 0.f};                                \
            const short* arow = &h1s[(jt * 16 + c) * HSTR + q * 8];          \
            _Pragma("unroll")                                                \
            for (int kb = 0; kb < 4; ++kb) {                                 \
                bf16x8 a = *(const bf16x8*)(arow + kb * 32);                 \
                acc = __builtin_amdgcn_mfma_f32_16x16x32_bf16(a, w2f[kb], acc, 0, 0, 0); \
            }                                                                \
            const int orow = jt * 16 + q * 4;                                \
            const unsigned p01 = cvt_pk_bf16(fmaxf(acc[0] + b2n, 0.0f),      \
                                             fmaxf(acc[1] + b2n, 0.0f));     \
            const unsigned p23 = cvt_pk_bf16(fmaxf(acc[2] + b2n, 0.0f),      \
                                             fmaxf(acc[3] + b2n, 0.0f));     \
            const unsigned send = (c & 1) ? p01 : p23;                       \
            const unsigned recv = __shfl_xor(send, 1, 64);                   \
            const unsigned keep = (c & 1) ? p23 : p01;                       \
            const unsigned lo = (c & 1) ? recv : keep;                       \
            const unsigned hi = (c & 1) ? keep : recv;                       \
            const unsigned d0 = (lo & 0xFFFFu) | (hi << 16);                 \
            const unsigned d1 = (lo >> 16) | (hi & 0xFFFF0000u);             \
            const int rbase = orow + ((c & 1) << 1);                         \
            const int colb = ncol & ~1;                                      \
            *(unsigned*)&h2s[(rbase + 0) * HSTR + colb] = d0;                \
            *(unsigned*)&h2s[(rbase + 1) * HSTR + colb] = d1;                \
        }                                                                    \
    } while (0)

#define GEMM2(c4_) do {                                                      \
        const int j0_ = (c4_) * 128;                                         \
        _Pragma("unroll")                                                    \
        for (int jt = 0; jt < 8; ++jt) {                                     \
            f32x4 acc = {0.f, 0.f, 0.f, 0.f};                                \
            const short* arow = &h2s[(jt * 16 + c) * HSTR + q * 8];          \
            _Pragma("unroll")                                                \
            for (int kb = 0; kb < 4; ++kb) {                                 \
                bf16x8 a = *(const bf16x8*)(arow + kb * 32);                 \
                acc = __builtin_amdgcn_mfma_f32_16x16x32_bf16(a, w3f[kb], acc, 0, 0, 0); \
            }                                                                \
            _Pragma("unroll")                                                \
            for (int r = 0; r < 4; ++r) {                                    \
                const int jg_ = j0_ + jt * 16 + q * 4 + r;                   \
                if (jg_ != i) psum += acc[r];                                \
            }                                                                \
        }                                                                    \
    } while (0)

    // pipelined: BUILD(c4+1) overlaps GEMM2(c4); h1s/h2s ping-pong by phase
    BUILD(0);
    __syncthreads();       // h1s(0) ready
    GEMM1();               // h1s(0) -> h2s(0)
    for (int c4 = 0; c4 < 4; ++c4) {
        __syncthreads();   // h2s(c4) ready; h1s free (GEMM1 done)
        if (c4 < 3) {
            BUILD(c4 + 1); // -> h1s (overlaps GEMM2's MFMAs)
            GEMM2(c4);     // h2s -> psum
            __syncthreads();  // h1s(c4+1) ready; h2s fully consumed
            GEMM1();       // h1s(c4+1) -> h2s(c4+1)
        } else {
            GEMM2(c4);
        }
    }
#undef BUILD
#undef GEMM1
#undef GEMM2

    // ---- msum: reduce over quads (same ncol), write straight into xs2 ----
    psum += __shfl_xor(psum, 16, 64);
    psum += __shfl_xor(psum, 32, 64);
    if (lane < 16) xs2[NH + ncol] = psum + 511.0f * b3[ncol];
    __syncthreads();

    // ---- tail: update MLP (fp32 GEMV, 4 lanes per output row) ----
    const int nn = t >> 2;   // output row 0..127
    const int ks = t & 3;    // k-segment
    // L1: K=256
    {
        const float* wr = uW1 + (size_t)nn * 256 + ks * 4;
        float p = 0.f;
        #pragma unroll
        for (int it = 0; it < 16; ++it) {
            const float4 wv = *(const float4*)(wr + it * 16);
            const float4 xv = *(const float4*)&xs2[it * 16 + ks * 4];
            p += wv.x * xv.x + wv.y * xv.y + wv.z * xv.z + wv.w * xv.w;
        }
        part[ks * NH + nn] = p;
    }
    __syncthreads();
    if (t < NH)
        hx[t] = fmaxf(ub1[t] + part[t] + part[NH + t] + part[2 * NH + t] + part[3 * NH + t], 0.f);
    __syncthreads();
    // L2: K=128
    {
        const float* wr = uW2 + (size_t)nn * NH + ks * 4;
        float p = 0.f;
        #pragma unroll
        for (int it = 0; it < 8; ++it) {
            const float4 wv = *(const float4*)(wr + it * 16);
            const float4 xv = *(const float4*)&hx[it * 16 + ks * 4];
            p += wv.x * xv.x + wv.y * xv.y + wv.z * xv.z + wv.w * xv.w;
        }
        part[ks * NH + nn] = p;
    }
    __syncthreads();
    if (t < NH)
        hy[t] = fmaxf(ub2[t] + part[t] + part[NH + t] + part[2 * NH + t] + part[3 * NH + t], 0.f);
    __syncthreads();
    // L3: K=128, no relu -> zout + hz
    {
        const float* wr = uW3 + (size_t)nn * NH + ks * 4;
        float p = 0.f;
        #pragma unroll
        for (int it = 0; it < 8; ++it) {
            const float4 wv = *(const float4*)(wr + it * 16);
            const float4 xv = *(const float4*)&hy[it * 16 + ks * 4];
            p += wv.x * xv.x + wv.y * xv.y + wv.z * xv.z + wv.w * xv.w;
        }
        part[ks * NH + nn] = p;
    }
    __syncthreads();
    if (t < NH) {
        const float v = ub3[t] + part[t] + part[NH + t] + part[2 * NH + t] + part[3 * NH + t];
        zout[(size_t)i * NH + t] = v;
        hz[t] = v;
    }
    if (!do_ab) return;
    __syncthreads();
    // ab: A = z@Wi^T, B = z@Wj^T (K=128, row stride 257 -> dword loads)
    {
        const float* pr = msgW1n + (size_t)nn * 257;
        float pa = 0.f, pb = 0.f;
        #pragma unroll
        for (int it = 0; it < 8; ++it) {
            #pragma unroll
            for (int j = 0; j < 4; ++j) {
                const int k = it * 16 + ks * 4 + j;
                const float x = hz[k];
                pa += x * pr[k];
                pb += x * pr[NH + k];
            }
        }
        part[ks * NH + nn] = pa;
        part2[ks * NH + nn] = pb;
    }
    __syncthreads();
    if (t < NH) {
        An[(size_t)i * NH + t] = part[t] + part[NH + t] + part[2 * NH + t] + part[3 * NH + t];
        Bn[(size_t)i * NH + t] = part2[t] + part2[NH + t] + part2[2 * NH + t] + part2[3 * NH + t];
    }
}

// ---------------------------------------------------------------- host ------
extern "C" void kernel_launch(void* const* d_in, const int* in_sizes, int n_in,
                              void* d_out, int out_size, void* d_ws, size_t ws_size,
                              hipStream_t stream) {
    fp32p obs   = (fp32p)d_in[0];
    fp32p pos   = (fp32p)d_in[1];
    fp32p encW1 = (fp32p)d_in[2];  fp32p encb1 = (fp32p)d_in[3];
    fp32p encW2 = (fp32p)d_in[4];  fp32p encb2 = (fp32p)d_in[5];
    fp32p encW3 = (fp32p)d_in[6];  fp32p encb3 = (fp32p)d_in[7];
    fp32p msgW1 = (fp32p)d_in[8];  fp32p msgb1 = (fp32p)d_in[9];
    fp32p msgW2 = (fp32p)d_in[10]; fp32p msgb2 = (fp32p)d_in[11];
    fp32p msgW3 = (fp32p)d_in[12]; fp32p msgb3 = (fp32p)d_in[13];
    fp32p updW1 = (fp32p)d_in[14]; fp32p updb1 = (fp32p)d_in[15];
    fp32p updW2 = (fp32p)d_in[16]; fp32p updb2 = (fp32p)d_in[17];
    fp32p updW3 = (fp32p)d_in[18]; fp32p updb3 = (fp32p)d_in[19];

    // workspace (fp32): zA | zB | A0 | B0 | A1 | B1  (1.5 MB)
    float* ws = (float*)d_ws;
    float* zA = ws;
    float* zB = zA + NA * NH;
    float* A0 = zB + NA * NH;
    float* B0 = A0 + NA * NH;
    float* A1 = B0 + NA * NH;
    float* B1 = A1 + NA * NH;

    enc_ab_kernel<<<NA / 16, 512, 0, stream>>>(obs, encW1, encb1, encW2, encb2,
                                               encW3, encb3, msgW1, zA, A0, B0);

    float* zin = zA;  float* zout = zB;
    float* Ac = A0;   float* Bc = B0;
    float* An = A1;   float* Bn = B1;
    for (int l = 0; l < 3; ++l) {
        const int do_ab = (l < 2);
        float* dst = (l == 2) ? (float*)d_out : zout;
        msg_upd_kernel<<<NA, 512, 0, stream>>>(Ac, Bc, pos, zin,
            msgW1 + (size_t)l * 128 * 257, msgb1 + l * 128,
            msgW2 + (size_t)l * 128 * 128, msgb2 + l * 128,
            msgW3 + (size_t)l * 128 * 128, msgb3 + l * 128,
            updW1 + (size_t)l * 256 * 128, updb1 + l * 128,
            updW2 + (size_t)l * 128 * 128, updb2 + l * 128,
            updW3 + (size_t)l * 128 * 128, updb3 + l * 128,
            msgW1 + (size_t)(l + 1 < 3 ? l + 1 : 0) * 128 * 257, do_ab,
            dst, An, Bn);
        float* tmp;
        tmp = zin; zin = zout; zout = tmp;
        tmp = Ac; Ac = An; An = tmp;
        tmp = Bc; Bc = Bn; Bn = tmp;
    }
}